// Round 4
// baseline (213.930 us; speedup 1.0000x reference)
//
#include <hip/hip_runtime.h>
#include <hip/hip_bf16.h>
#include <cstdint>
#include <cstddef>

typedef __bf16 bf16;
typedef bf16 bf16x2 __attribute__((ext_vector_type(2)));
typedef bf16 bf16x4 __attribute__((ext_vector_type(4)));
typedef bf16 bf16x8 __attribute__((ext_vector_type(8)));
typedef float f32x4 __attribute__((ext_vector_type(4)));
typedef float f32x16 __attribute__((ext_vector_type(16)));

#define SEQ 2048
#define EMB 1024
#define NH 16
#define HD 64
#define BSZ 2
#define MROWS (BSZ*SEQ)   // 4096

__device__ __forceinline__ void gload_lds16(const void* g, void* lds) {
  __builtin_amdgcn_global_load_lds((__attribute__((address_space(1))) void*)g,
                                   (__attribute__((address_space(3))) void*)lds,
                                   16, 0, 0);
}

// ---------------- f32 -> bf16 convert (vectorized) ----------------
__global__ void cvt_kernel(const float* __restrict__ src, bf16* __restrict__ dst, int n4) {
  int i = blockIdx.x * blockDim.x + threadIdx.x;
  if (i >= n4) return;
  const float4 v = reinterpret_cast<const float4*>(src)[i];
  bf16x4 o;
  o[0] = (bf16)v.x; o[1] = (bf16)v.y; o[2] = (bf16)v.z; o[3] = (bf16)v.w;
  reinterpret_cast<bf16x4*>(dst)[i] = o;
}

// ---------------- RoPE tables ----------------
__global__ void rope_tables_kernel(float* __restrict__ cosT, float* __restrict__ sinT) {
  int idx = blockIdx.x * blockDim.x + threadIdx.x; // s*32 + j
  if (idx >= SEQ * 32) return;
  int s = idx >> 5, j = idx & 31;
  float ex = (2.0f * (float)j) / 64.0f;
  float inv = 1.0f / powf(10000.0f, ex);
  float ang = (float)s * inv;
  cosT[idx] = cosf(ang);
  sinT[idx] = sinf(ang);
}

// ---------------- RoPE apply (in place; q additionally scaled by 1/8) ----------------
__global__ void rope_apply_kernel(bf16* __restrict__ qb, bf16* __restrict__ kb,
                                  const float* __restrict__ cosT, const float* __restrict__ sinT) {
  int idx = blockIdx.x * blockDim.x + threadIdx.x; // over BSZ*NH*SEQ*32 pairs
  if (idx >= BSZ * NH * SEQ * 32) return;
  int j = idx & 31;
  int s = (idx >> 5) & (SEQ - 1);
  int bh = idx >> 16;                       // SEQ*32 = 65536 per (b,h)
  float c = cosT[(s << 5) + j], sn = sinT[(s << 5) + j];
  size_t base = ((size_t)bh * SEQ + s) * HD + 2 * j;
  float q0 = (float)qb[base], q1 = (float)qb[base + 1];
  // fold softmax scale 1/sqrt(64)=0.125 into q (exact: exponent shift)
  qb[base]     = (bf16)((q0 * c - q1 * sn) * 0.125f);
  qb[base + 1] = (bf16)((q0 * sn + q1 * c) * 0.125f);
  float k0 = (float)kb[base], k1 = (float)kb[base + 1];
  kb[base]     = (bf16)(k0 * c - k1 * sn);
  kb[base + 1] = (bf16)(k0 * sn + k1 * c);
}

// ---------------- GEMM C = A @ B^T (+bias), 128x128 tile, bf16 MFMA ----------------
// A: (M,K) bf16 row-major. B: (N,K) bf16 row-major. EPI=0: f32 out. EPI=1: qkv scatter.
template<int EPI>
__launch_bounds__(256)
__global__ void gemm_bt(const bf16* __restrict__ A, const bf16* __restrict__ B,
                        const float* __restrict__ bias,
                        float* __restrict__ Cf,
                        bf16* __restrict__ qb, bf16* __restrict__ kb, bf16* __restrict__ vt,
                        int Ndim, int Kdim) {
  __shared__ __align__(16) bf16 Alds[128 * 32];
  __shared__ __align__(16) bf16 Blds[128 * 32];
  const int tid = threadIdx.x;
  const int wave = tid >> 6, lane = tid & 63;
  const int wr = wave >> 1, wc = wave & 1;
  const int bm = blockIdx.x * 128, bn = blockIdx.y * 128;

  f32x4 acc[4][4] = {};

  const int srow = lane >> 2;        // 0..15 within 16-row chunk
  const int scol = (lane & 3) * 8;   // element col within 32-wide tile
  char* aldsb = (char*)Alds;
  char* bldsb = (char*)Blds;

  for (int kt = 0; kt < Kdim; kt += 32) {
    gload_lds16(A + (size_t)(bm + wave * 16 + srow) * Kdim + kt + scol, aldsb + wave * 1024);
    gload_lds16(A + (size_t)(bm + (wave + 4) * 16 + srow) * Kdim + kt + scol, aldsb + wave * 1024 + 4096);
    gload_lds16(B + (size_t)(bn + wave * 16 + srow) * Kdim + kt + scol, bldsb + wave * 1024);
    gload_lds16(B + (size_t)(bn + (wave + 4) * 16 + srow) * Kdim + kt + scol, bldsb + wave * 1024 + 4096);
    __syncthreads();
    bf16x8 af[4], bfr[4];
#pragma unroll
    for (int m = 0; m < 4; m++)
      af[m] = *reinterpret_cast<const bf16x8*>(Alds + (wr * 64 + m * 16 + (lane & 15)) * 32 + (lane >> 4) * 8);
#pragma unroll
    for (int n = 0; n < 4; n++)
      bfr[n] = *reinterpret_cast<const bf16x8*>(Blds + (wc * 64 + n * 16 + (lane & 15)) * 32 + (lane >> 4) * 8);
#pragma unroll
    for (int m = 0; m < 4; m++)
#pragma unroll
      for (int n = 0; n < 4; n++)
        acc[m][n] = __builtin_amdgcn_mfma_f32_16x16x32_bf16(af[m], bfr[n], acc[m][n], 0, 0, 0);
    __syncthreads();
  }

#pragma unroll
  for (int m = 0; m < 4; m++) {
#pragma unroll
    for (int n = 0; n < 4; n++) {
#pragma unroll
      for (int r = 0; r < 4; r++) {
        const int row = bm + wr * 64 + m * 16 + (lane >> 4) * 4 + r;
        const int col = bn + wc * 64 + n * 16 + (lane & 15);
        const float v = acc[m][n][r] + bias[col];
        if (EPI == 0) {
          Cf[(size_t)row * Ndim + col] = v;
        } else {
          const int b = row >> 11, s = row & (SEQ - 1);
          const int which = col >> 10, rem = col & 1023;
          const int h = rem >> 6, d = rem & 63;
          const bf16 bv = (bf16)v;
          if (which == 0)      qb[(((size_t)(b * NH + h) * SEQ) + s) * HD + d] = bv;
          else if (which == 1) kb[(((size_t)(b * NH + h) * SEQ) + s) * HD + d] = bv;
          else                 vt[(((size_t)(b * NH + h) * HD) + d) * SEQ + s] = bv;  // V transposed
        }
      }
    }
  }
}

// ---------------- Flash attention, swapped-QK^T 32x32, softmax fully in-register --------
// Per wave: 32 q-rows. No LDS, no barriers. XCD-swizzled blocks (K/V L2-resident),
// register double-buffered K/V prefetch, defer-max rescale skip.
__device__ __forceinline__ unsigned pk2(float a, float b) {
  bf16x2 t; t[0] = (bf16)a; t[1] = (bf16)b;
  unsigned u; __builtin_memcpy(&u, &t, 4); return u;
}

#define LOADK(DST, KV0) do { \
  _Pragma("unroll") \
  for (int dk = 0; dk < 4; dk++) \
    DST[dk] = *reinterpret_cast<const bf16x8*>(Kb + (size_t)((KV0) + ql) * HD + dk * 16 + hi * 8); \
} while (0)

// VF[i]: i = dtile*2 + ks  (dtile in {0,1} over d, ks in {0,1} over k-halves)
#define LOADV(DST, KV0) do { \
  _Pragma("unroll") \
  for (int i = 0; i < 4; i++) \
    DST[i] = *reinterpret_cast<const bf16x8*>(Vb + (size_t)((i >> 1) * 32 + ql) * SEQ + (KV0) + (i & 1) * 16 + hi * 8); \
} while (0)

#define COMPUTE(KF, VF) do { \
  f32x16 s = {}; \
  _Pragma("unroll") \
  for (int dk = 0; dk < 4; dk++) \
    s = __builtin_amdgcn_mfma_f32_32x32x16_bf16(KF[dk], qf[dk], s, 0, 0, 0); \
  float mx = s[0]; \
  _Pragma("unroll") \
  for (int r = 1; r < 16; r++) mx = fmaxf(mx, s[r]); \
  mx = fmaxf(mx, __shfl_xor(mx, 32, 64)); \
  if (!__all(mx <= mrun + 8.f)) { \
    const float mnew = fmaxf(mrun, mx); \
    const float alpha = __expf(mrun - mnew); \
    mrun = mnew; \
    lrun *= alpha; \
    _Pragma("unroll") \
    for (int r = 0; r < 16; r++) { oacc0[r] *= alpha; oacc1[r] *= alpha; } \
  } \
  float p[16]; \
  float rsum = 0.f; \
  _Pragma("unroll") \
  for (int r = 0; r < 16; r++) { p[r] = __expf(s[r] - mrun); rsum += p[r]; } \
  rsum += __shfl_xor(rsum, 32, 64); \
  lrun += rsum; \
  const unsigned a0 = pk2(p[0], p[1]),   a1 = pk2(p[2], p[3]); \
  const unsigned a2 = pk2(p[4], p[5]),   a3 = pk2(p[6], p[7]); \
  const unsigned b0 = pk2(p[8], p[9]),   b1 = pk2(p[10], p[11]); \
  const unsigned b2 = pk2(p[12], p[13]), b3 = pk2(p[14], p[15]); \
  const unsigned sa = hi ? a0 : a2; \
  const unsigned sb = hi ? a1 : a3; \
  const unsigned sc = hi ? b0 : b2; \
  const unsigned sd = hi ? b1 : b3; \
  const unsigned ta = (unsigned)__shfl_xor((int)sa, 32, 64); \
  const unsigned tb = (unsigned)__shfl_xor((int)sb, 32, 64); \
  const unsigned tc = (unsigned)__shfl_xor((int)sc, 32, 64); \
  const unsigned td = (unsigned)__shfl_xor((int)sd, 32, 64); \
  unsigned w[8]; \
  w[0] = hi ? ta : a0;  w[1] = hi ? tb : a1; \
  w[2] = hi ? a2 : ta;  w[3] = hi ? a3 : tb; \
  w[4] = hi ? tc : b0;  w[5] = hi ? td : b1; \
  w[6] = hi ? b2 : tc;  w[7] = hi ? b3 : td; \
  bf16x8 pf0, pf1; \
  __builtin_memcpy(&pf0, &w[0], 16); \
  __builtin_memcpy(&pf1, &w[4], 16); \
  oacc0 = __builtin_amdgcn_mfma_f32_32x32x16_bf16(VF[0], pf0, oacc0, 0, 0, 0); \
  oacc1 = __builtin_amdgcn_mfma_f32_32x32x16_bf16(VF[2], pf0, oacc1, 0, 0, 0); \
  oacc0 = __builtin_amdgcn_mfma_f32_32x32x16_bf16(VF[1], pf1, oacc0, 0, 0, 0); \
  oacc1 = __builtin_amdgcn_mfma_f32_32x32x16_bf16(VF[3], pf1, oacc1, 0, 0, 0); \
} while (0)

__launch_bounds__(256)
__global__ void attn_kernel(const bf16* __restrict__ qb, const bf16* __restrict__ kb,
                            const bf16* __restrict__ vt, bf16* __restrict__ ob) {
  // XCD swizzle: 512 blocks = 8 XCDs x 64. XCD x gets heads [x*4,(x+1)*4):
  // K+V working set per XCD = 4 heads * 512KB = 2MB < 4MB L2.
  const int bid = (blockIdx.x & 7) * 64 + (blockIdx.x >> 3);
  const int qblk = bid & 15;          // 16 blocks of 128 q-rows per (b,h)
  const int bh = bid >> 4;
  const int b = bh >> 4, h = bh & 15;
  const int wave = threadIdx.x >> 6, lane = threadIdx.x & 63;
  const int q0 = qblk * 128 + wave * 32;
  const int ql = lane & 31, hi = lane >> 5;

  const bf16* Qb = qb + (size_t)bh * SEQ * HD;
  const bf16* Kb = kb + (size_t)bh * SEQ * HD;
  const bf16* Vb = vt + (size_t)bh * HD * SEQ;

  // Q fragments (B-operand): lane holds col q=ql, d = dk*16 + hi*8 + j
  bf16x8 qf[4];
#pragma unroll
  for (int dk = 0; dk < 4; dk++)
    qf[dk] = *reinterpret_cast<const bf16x8*>(Qb + (size_t)(q0 + ql) * HD + dk * 16 + hi * 8);

  f32x16 oacc0 = {}, oacc1 = {};   // O^T d-tiles [0,32) and [32,64)
  float mrun = -1e30f, lrun = 0.f;

  bf16x8 kA[4], vA[4], kB[4], vB[4];
  LOADK(kA, 0); LOADV(vA, 0);
  for (int kv = 0; kv < SEQ; kv += 64) {
    LOADK(kB, kv + 32); LOADV(vB, kv + 32);      // prefetch tile t+1
    COMPUTE(kA, vA);                              // compute tile t
    const int nxt = (kv + 64) & (SEQ - 1);        // wrap: harmless re-read of tile 0 at end
    LOADK(kA, nxt); LOADV(vA, nxt);               // prefetch tile t+2
    COMPUTE(kB, vB);                              // compute tile t+1
  }

  const float inv = 1.0f / lrun;
  const size_t orow = ((size_t)b * SEQ + q0 + ql) * EMB + h * HD;
#pragma unroll
  for (int r = 0; r < 16; r++) {
    const int d = (r & 3) + 8 * (r >> 2) + 4 * hi;
    ob[orow + d]      = (bf16)(oacc0[r] * inv);
    ob[orow + 32 + d] = (bf16)(oacc1[r] * inv);
  }
}

extern "C" void kernel_launch(void* const* d_in, const int* in_sizes, int n_in,
                              void* d_out, int out_size, void* d_ws, size_t ws_size,
                              hipStream_t stream) {
  const float* x    = (const float*)d_in[0];   // query (reference only uses query)
  const float* Win  = (const float*)d_in[3];   // (3E, E)
  const float* bin  = (const float*)d_in[4];   // (3E,)
  const float* Wout = (const float*)d_in[5];   // (E, E)
  const float* bout = (const float*)d_in[6];   // (E,)
  float* out = (float*)d_out;

  char* p = (char*)d_ws;
  bf16* xb  = (bf16*)p; p += (size_t)MROWS * EMB * 2;       // 8 MB
  bf16* wb  = (bf16*)p; p += (size_t)3 * EMB * EMB * 2;     // 6 MB
  bf16* wob = (bf16*)p; p += (size_t)EMB * EMB * 2;         // 2 MB
  bf16* qb  = (bf16*)p; p += (size_t)MROWS * EMB * 2;       // 8 MB (B,H,S,D)
  bf16* kb  = (bf16*)p; p += (size_t)MROWS * EMB * 2;       // 8 MB (B,H,S,D)
  bf16* vt  = (bf16*)p; p += (size_t)MROWS * EMB * 2;       // 8 MB (B,H,D,S)
  bf16* ob  = (bf16*)p; p += (size_t)MROWS * EMB * 2;       // 8 MB (B,S,E)
  float* cosT = (float*)p; p += (size_t)SEQ * 32 * 4;
  float* sinT = (float*)p; p += (size_t)SEQ * 32 * 4;

  cvt_kernel<<<(MROWS * EMB / 4 + 255) / 256, 256, 0, stream>>>(x, xb, MROWS * EMB / 4);
  cvt_kernel<<<(3 * EMB * EMB / 4 + 255) / 256, 256, 0, stream>>>(Win, wb, 3 * EMB * EMB / 4);
  cvt_kernel<<<(EMB * EMB / 4 + 255) / 256, 256, 0, stream>>>(Wout, wob, EMB * EMB / 4);
  rope_tables_kernel<<<(SEQ * 32 + 255) / 256, 256, 0, stream>>>(cosT, sinT);

  gemm_bt<1><<<dim3(MROWS / 128, 3 * EMB / 128), 256, 0, stream>>>(
      xb, wb, bin, nullptr, qb, kb, vt, 3 * EMB, EMB);
  rope_apply_kernel<<<(BSZ * NH * SEQ * 32 + 255) / 256, 256, 0, stream>>>(qb, kb, cosT, sinT);
  attn_kernel<<<BSZ * NH * (SEQ / 128), 256, 0, stream>>>(qb, kb, vt, ob);
  gemm_bt<0><<<dim3(MROWS / 128, EMB / 128), 256, 0, stream>>>(
      ob, wob, bout, out, nullptr, nullptr, nullptr, EMB, EMB);
}

// Round 5
// 156.051 us; speedup vs baseline: 1.3709x; 1.3709x over previous
//
#include <hip/hip_runtime.h>
#include <hip/hip_bf16.h>
#include <cstdint>
#include <cstddef>

typedef __bf16 bf16;
typedef bf16 bf16x2 __attribute__((ext_vector_type(2)));
typedef bf16 bf16x4 __attribute__((ext_vector_type(4)));
typedef bf16 bf16x8 __attribute__((ext_vector_type(8)));
typedef float f32x4 __attribute__((ext_vector_type(4)));
typedef float f32x16 __attribute__((ext_vector_type(16)));

#define SEQ 2048
#define EMB 1024
#define NH 16
#define HD 64
#define BSZ 2
#define MROWS (BSZ*SEQ)   // 4096

__device__ __forceinline__ void gload_lds16(const void* g, void* lds) {
  __builtin_amdgcn_global_load_lds((__attribute__((address_space(1))) void*)g,
                                   (__attribute__((address_space(3))) void*)lds,
                                   16, 0, 0);
}

// ---------------- f32 -> bf16 convert (vectorized) ----------------
__global__ void cvt_kernel(const float* __restrict__ src, bf16* __restrict__ dst, int n4) {
  int i = blockIdx.x * blockDim.x + threadIdx.x;
  if (i >= n4) return;
  const float4 v = reinterpret_cast<const float4*>(src)[i];
  bf16x4 o;
  o[0] = (bf16)v.x; o[1] = (bf16)v.y; o[2] = (bf16)v.z; o[3] = (bf16)v.w;
  reinterpret_cast<bf16x4*>(dst)[i] = o;
}

// ---------------- RoPE tables ----------------
__global__ void rope_tables_kernel(float* __restrict__ cosT, float* __restrict__ sinT) {
  int idx = blockIdx.x * blockDim.x + threadIdx.x; // s*32 + j
  if (idx >= SEQ * 32) return;
  int s = idx >> 5, j = idx & 31;
  float ex = (2.0f * (float)j) / 64.0f;
  float inv = 1.0f / powf(10000.0f, ex);
  float ang = (float)s * inv;
  cosT[idx] = cosf(ang);
  sinT[idx] = sinf(ang);
}

// ---------------- RoPE apply (in place; q additionally scaled by 1/8) ----------------
__global__ void rope_apply_kernel(bf16* __restrict__ qb, bf16* __restrict__ kb,
                                  const float* __restrict__ cosT, const float* __restrict__ sinT) {
  int idx = blockIdx.x * blockDim.x + threadIdx.x; // over BSZ*NH*SEQ*32 pairs
  if (idx >= BSZ * NH * SEQ * 32) return;
  int j = idx & 31;
  int s = (idx >> 5) & (SEQ - 1);
  int bh = idx >> 16;                       // SEQ*32 = 65536 per (b,h)
  float c = cosT[(s << 5) + j], sn = sinT[(s << 5) + j];
  size_t base = ((size_t)bh * SEQ + s) * HD + 2 * j;
  float q0 = (float)qb[base], q1 = (float)qb[base + 1];
  // fold softmax scale 1/sqrt(64)=0.125 into q (exact: exponent shift)
  qb[base]     = (bf16)((q0 * c - q1 * sn) * 0.125f);
  qb[base + 1] = (bf16)((q0 * sn + q1 * c) * 0.125f);
  float k0 = (float)kb[base], k1 = (float)kb[base + 1];
  kb[base]     = (bf16)(k0 * c - k1 * sn);
  kb[base + 1] = (bf16)(k0 * sn + k1 * c);
}

// ---------------- GEMM C = A @ B^T (+bias), 128x128 tile, bf16 MFMA ----------------
// A: (M,K) bf16 row-major. B: (N,K) bf16 row-major. EPI=0: f32 out. EPI=1: qkv scatter.
template<int EPI>
__launch_bounds__(256)
__global__ void gemm_bt(const bf16* __restrict__ A, const bf16* __restrict__ B,
                        const float* __restrict__ bias,
                        float* __restrict__ Cf,
                        bf16* __restrict__ qb, bf16* __restrict__ kb, bf16* __restrict__ vt,
                        int Ndim, int Kdim) {
  __shared__ __align__(16) bf16 Alds[128 * 32];
  __shared__ __align__(16) bf16 Blds[128 * 32];
  const int tid = threadIdx.x;
  const int wave = tid >> 6, lane = tid & 63;
  const int wr = wave >> 1, wc = wave & 1;
  const int bm = blockIdx.x * 128, bn = blockIdx.y * 128;

  f32x4 acc[4][4] = {};

  const int srow = lane >> 2;        // 0..15 within 16-row chunk
  const int scol = (lane & 3) * 8;   // element col within 32-wide tile
  char* aldsb = (char*)Alds;
  char* bldsb = (char*)Blds;

  for (int kt = 0; kt < Kdim; kt += 32) {
    gload_lds16(A + (size_t)(bm + wave * 16 + srow) * Kdim + kt + scol, aldsb + wave * 1024);
    gload_lds16(A + (size_t)(bm + (wave + 4) * 16 + srow) * Kdim + kt + scol, aldsb + wave * 1024 + 4096);
    gload_lds16(B + (size_t)(bn + wave * 16 + srow) * Kdim + kt + scol, bldsb + wave * 1024);
    gload_lds16(B + (size_t)(bn + (wave + 4) * 16 + srow) * Kdim + kt + scol, bldsb + wave * 1024 + 4096);
    __syncthreads();
    bf16x8 af[4], bfr[4];
#pragma unroll
    for (int m = 0; m < 4; m++)
      af[m] = *reinterpret_cast<const bf16x8*>(Alds + (wr * 64 + m * 16 + (lane & 15)) * 32 + (lane >> 4) * 8);
#pragma unroll
    for (int n = 0; n < 4; n++)
      bfr[n] = *reinterpret_cast<const bf16x8*>(Blds + (wc * 64 + n * 16 + (lane & 15)) * 32 + (lane >> 4) * 8);
#pragma unroll
    for (int m = 0; m < 4; m++)
#pragma unroll
      for (int n = 0; n < 4; n++)
        acc[m][n] = __builtin_amdgcn_mfma_f32_16x16x32_bf16(af[m], bfr[n], acc[m][n], 0, 0, 0);
    __syncthreads();
  }

#pragma unroll
  for (int m = 0; m < 4; m++) {
#pragma unroll
    for (int n = 0; n < 4; n++) {
#pragma unroll
      for (int r = 0; r < 4; r++) {
        const int row = bm + wr * 64 + m * 16 + (lane >> 4) * 4 + r;
        const int col = bn + wc * 64 + n * 16 + (lane & 15);
        const float v = acc[m][n][r] + bias[col];
        if (EPI == 0) {
          Cf[(size_t)row * Ndim + col] = v;
        } else {
          const int b = row >> 11, s = row & (SEQ - 1);
          const int which = col >> 10, rem = col & 1023;
          const int h = rem >> 6, d = rem & 63;
          const bf16 bv = (bf16)v;
          if (which == 0)      qb[(((size_t)(b * NH + h) * SEQ) + s) * HD + d] = bv;
          else if (which == 1) kb[(((size_t)(b * NH + h) * SEQ) + s) * HD + d] = bv;
          else                 vt[(((size_t)(b * NH + h) * HD) + d) * SEQ + s] = bv;  // V transposed
        }
      }
    }
  }
}

// ---------------- Flash attention, swapped-QK^T 32x32, LDS-staged K/V ----------------
// 4 waves x 32 q-rows. KVBLK=64 tiles cooperatively staged (coalesced), double-buffered
// LDS (pitch 144B: 16B-aligned, 4-way max conflict). Softmax in-register, XCD swizzle,
// defer-max, T14 load-early/write-late.
__device__ __forceinline__ unsigned pk2(float a, float b) {
  bf16x2 t; t[0] = (bf16)a; t[1] = (bf16)b;
  unsigned u; __builtin_memcpy(&u, &t, 4); return u;
}

#define KPITCH 144

#define STAGE_LOAD(KV0) do { \
  kr0 = *(const int4*)(Kb + (size_t)((KV0) + (tid >> 3)) * HD + (tid & 7) * 8); \
  kr1 = *(const int4*)(Kb + (size_t)((KV0) + 32 + (tid >> 3)) * HD + (tid & 7) * 8); \
  vr0 = *(const int4*)(Vb + (size_t)(tid >> 3) * SEQ + (KV0) + (tid & 7) * 8); \
  vr1 = *(const int4*)(Vb + (size_t)(32 + (tid >> 3)) * SEQ + (KV0) + (tid & 7) * 8); \
} while (0)

#define STAGE_WRITE(BUF) do { \
  *(int4*)(Klds[BUF] + (tid >> 3) * KPITCH + (tid & 7) * 16) = kr0; \
  *(int4*)(Klds[BUF] + ((tid >> 3) + 32) * KPITCH + (tid & 7) * 16) = kr1; \
  *(int4*)(Vlds[BUF] + (tid >> 3) * KPITCH + (tid & 7) * 16) = vr0; \
  *(int4*)(Vlds[BUF] + ((tid >> 3) + 32) * KPITCH + (tid & 7) * 16) = vr1; \
} while (0)

#define COMPUTE_LDS(KB, VB, KS32) do { \
  const char* kbp = (KB); const char* vbp = (VB); \
  bf16x8 KF[4]; \
  _Pragma("unroll") \
  for (int dk = 0; dk < 4; dk++) \
    KF[dk] = *reinterpret_cast<const bf16x8*>(kbp + ((KS32) + ql) * KPITCH + dk * 32 + hi * 16); \
  f32x16 s = {}; \
  _Pragma("unroll") \
  for (int dk = 0; dk < 4; dk++) \
    s = __builtin_amdgcn_mfma_f32_32x32x16_bf16(KF[dk], qf[dk], s, 0, 0, 0); \
  bf16x8 VF[4]; \
  _Pragma("unroll") \
  for (int i = 0; i < 4; i++) \
    VF[i] = *reinterpret_cast<const bf16x8*>(vbp + ((i >> 1) * 32 + ql) * KPITCH + ((KS32) + (i & 1) * 16 + hi * 8) * 2); \
  float tm[8]; \
  _Pragma("unroll") \
  for (int r = 0; r < 8; r++) tm[r] = fmaxf(s[2 * r], s[2 * r + 1]); \
  _Pragma("unroll") \
  for (int r = 0; r < 4; r++) tm[r] = fmaxf(tm[2 * r], tm[2 * r + 1]); \
  tm[0] = fmaxf(tm[0], tm[1]); tm[1] = fmaxf(tm[2], tm[3]); \
  float mx = fmaxf(tm[0], tm[1]); \
  mx = fmaxf(mx, __shfl_xor(mx, 32, 64)); \
  if (!__all(mx <= mrun + 8.f)) { \
    const float mnew = fmaxf(mrun, mx); \
    const float alpha = __expf(mrun - mnew); \
    mrun = mnew; \
    lrun *= alpha; \
    _Pragma("unroll") \
    for (int r = 0; r < 16; r++) { oacc0[r] *= alpha; oacc1[r] *= alpha; } \
  } \
  float p[16]; \
  _Pragma("unroll") \
  for (int r = 0; r < 16; r++) p[r] = __expf(s[r] - mrun); \
  float ts[8]; \
  _Pragma("unroll") \
  for (int r = 0; r < 8; r++) ts[r] = p[2 * r] + p[2 * r + 1]; \
  _Pragma("unroll") \
  for (int r = 0; r < 4; r++) ts[r] = ts[2 * r] + ts[2 * r + 1]; \
  float rsum = (ts[0] + ts[1]) + (ts[2] + ts[3]); \
  rsum += __shfl_xor(rsum, 32, 64); \
  lrun += rsum; \
  const unsigned a0 = pk2(p[0], p[1]),   a1 = pk2(p[2], p[3]); \
  const unsigned a2 = pk2(p[4], p[5]),   a3 = pk2(p[6], p[7]); \
  const unsigned b0 = pk2(p[8], p[9]),   b1 = pk2(p[10], p[11]); \
  const unsigned b2 = pk2(p[12], p[13]), b3 = pk2(p[14], p[15]); \
  const unsigned sa = hi ? a0 : a2; \
  const unsigned sb = hi ? a1 : a3; \
  const unsigned sc = hi ? b0 : b2; \
  const unsigned sd = hi ? b1 : b3; \
  const unsigned ta = (unsigned)__shfl_xor((int)sa, 32, 64); \
  const unsigned tb = (unsigned)__shfl_xor((int)sb, 32, 64); \
  const unsigned tc = (unsigned)__shfl_xor((int)sc, 32, 64); \
  const unsigned td = (unsigned)__shfl_xor((int)sd, 32, 64); \
  unsigned w[8]; \
  w[0] = hi ? ta : a0;  w[1] = hi ? tb : a1; \
  w[2] = hi ? a2 : ta;  w[3] = hi ? a3 : tb; \
  w[4] = hi ? tc : b0;  w[5] = hi ? td : b1; \
  w[6] = hi ? b2 : tc;  w[7] = hi ? b3 : td; \
  bf16x8 pf0, pf1; \
  __builtin_memcpy(&pf0, &w[0], 16); \
  __builtin_memcpy(&pf1, &w[4], 16); \
  oacc0 = __builtin_amdgcn_mfma_f32_32x32x16_bf16(VF[0], pf0, oacc0, 0, 0, 0); \
  oacc1 = __builtin_amdgcn_mfma_f32_32x32x16_bf16(VF[2], pf0, oacc1, 0, 0, 0); \
  oacc0 = __builtin_amdgcn_mfma_f32_32x32x16_bf16(VF[1], pf1, oacc0, 0, 0, 0); \
  oacc1 = __builtin_amdgcn_mfma_f32_32x32x16_bf16(VF[3], pf1, oacc1, 0, 0, 0); \
} while (0)

__launch_bounds__(256)
__global__ void attn_kernel(const bf16* __restrict__ qb, const bf16* __restrict__ kb,
                            const bf16* __restrict__ vt, bf16* __restrict__ ob) {
  // XCD swizzle: 512 blocks = 8 XCDs x 64. XCD x gets heads [x*4,(x+1)*4):
  // K+V working set per XCD = 4 heads * 512KB = 2MB < 4MB L2.
  const int bid = (blockIdx.x & 7) * 64 + (blockIdx.x >> 3);
  const int qblk = bid & 15;          // 16 blocks of 128 q-rows per (b,h)
  const int bh = bid >> 4;
  const int b = bh >> 4, h = bh & 15;
  const int tid = threadIdx.x;
  const int wave = tid >> 6, lane = tid & 63;
  const int q0 = qblk * 128 + wave * 32;
  const int ql = lane & 31, hi = lane >> 5;

  __shared__ __align__(16) char Klds[2][64 * KPITCH];
  __shared__ __align__(16) char Vlds[2][64 * KPITCH];

  const bf16* Qb = qb + (size_t)bh * SEQ * HD;
  const bf16* Kb = kb + (size_t)bh * SEQ * HD;
  const bf16* Vb = vt + (size_t)bh * HD * SEQ;

  // Q fragments (B-operand): lane holds col q=ql, d = dk*16 + hi*8 + j
  bf16x8 qf[4];
#pragma unroll
  for (int dk = 0; dk < 4; dk++)
    qf[dk] = *reinterpret_cast<const bf16x8*>(Qb + (size_t)(q0 + ql) * HD + dk * 16 + hi * 8);

  f32x16 oacc0 = {}, oacc1 = {};   // O^T d-tiles [0,32) and [32,64)
  float mrun = -1e30f, lrun = 0.f;

  int4 kr0, kr1, vr0, vr1;
  STAGE_LOAD(0);
  STAGE_WRITE(0);
  __syncthreads();

  for (int t = 0; t < SEQ / 64; ++t) {
    const int cur = t & 1;
    if (t < SEQ / 64 - 1) STAGE_LOAD((t + 1) * 64);   // T14: issue early, covered by compute
    COMPUTE_LDS(Klds[cur], Vlds[cur], 0);
    COMPUTE_LDS(Klds[cur], Vlds[cur], 32);
    __syncthreads();                                   // all waves done reading buf[cur^1..]
    if (t < SEQ / 64 - 1) {
      STAGE_WRITE(cur ^ 1);                            // write-late (after barrier)
      __syncthreads();
    }
  }

  const float inv = 1.0f / lrun;
  const size_t orow = ((size_t)b * SEQ + q0 + ql) * EMB + h * HD;
#pragma unroll
  for (int r = 0; r < 16; r++) {
    const int d = (r & 3) + 8 * (r >> 2) + 4 * hi;
    ob[orow + d]      = (bf16)(oacc0[r] * inv);
    ob[orow + 32 + d] = (bf16)(oacc1[r] * inv);
  }
}

extern "C" void kernel_launch(void* const* d_in, const int* in_sizes, int n_in,
                              void* d_out, int out_size, void* d_ws, size_t ws_size,
                              hipStream_t stream) {
  const float* x    = (const float*)d_in[0];   // query (reference only uses query)
  const float* Win  = (const float*)d_in[3];   // (3E, E)
  const float* bin  = (const float*)d_in[4];   // (3E,)
  const float* Wout = (const float*)d_in[5];   // (E, E)
  const float* bout = (const float*)d_in[6];   // (E,)
  float* out = (float*)d_out;

  char* p = (char*)d_ws;
  bf16* xb  = (bf16*)p; p += (size_t)MROWS * EMB * 2;       // 8 MB
  bf16* wb  = (bf16*)p; p += (size_t)3 * EMB * EMB * 2;     // 6 MB
  bf16* wob = (bf16*)p; p += (size_t)EMB * EMB * 2;         // 2 MB
  bf16* qb  = (bf16*)p; p += (size_t)MROWS * EMB * 2;       // 8 MB (B,H,S,D)
  bf16* kb  = (bf16*)p; p += (size_t)MROWS * EMB * 2;       // 8 MB (B,H,S,D)
  bf16* vt  = (bf16*)p; p += (size_t)MROWS * EMB * 2;       // 8 MB (B,H,D,S)
  bf16* ob  = (bf16*)p; p += (size_t)MROWS * EMB * 2;       // 8 MB (B,S,E)
  float* cosT = (float*)p; p += (size_t)SEQ * 32 * 4;
  float* sinT = (float*)p; p += (size_t)SEQ * 32 * 4;

  cvt_kernel<<<(MROWS * EMB / 4 + 255) / 256, 256, 0, stream>>>(x, xb, MROWS * EMB / 4);
  cvt_kernel<<<(3 * EMB * EMB / 4 + 255) / 256, 256, 0, stream>>>(Win, wb, 3 * EMB * EMB / 4);
  cvt_kernel<<<(EMB * EMB / 4 + 255) / 256, 256, 0, stream>>>(Wout, wob, EMB * EMB / 4);
  rope_tables_kernel<<<(SEQ * 32 + 255) / 256, 256, 0, stream>>>(cosT, sinT);

  gemm_bt<1><<<dim3(MROWS / 128, 3 * EMB / 128), 256, 0, stream>>>(
      xb, wb, bin, nullptr, qb, kb, vt, 3 * EMB, EMB);
  rope_apply_kernel<<<(BSZ * NH * SEQ * 32 + 255) / 256, 256, 0, stream>>>(qb, kb, cosT, sinT);
  attn_kernel<<<BSZ * NH * (SEQ / 128), 256, 0, stream>>>(qb, kb, vt, ob);
  gemm_bt<0><<<dim3(MROWS / 128, EMB / 128), 256, 0, stream>>>(
      ob, wob, bout, out, nullptr, nullptr, nullptr, EMB, EMB);
}